// Round 4
// baseline (318.071 us; speedup 1.0000x reference)
//
#include <hip/hip_runtime.h>

typedef __attribute__((ext_vector_type(8))) short short8;
typedef __attribute__((ext_vector_type(4))) short bf16x4;
typedef __attribute__((ext_vector_type(4))) float float4v;

#define D_MODEL 512
#define NUM_HEADS 8
#define DEPTH 64
#define SEQ 4096
#define BATCH 2
#define MROWS 8192
#define WSZ (D_MODEL * D_MODEL) // 262144
// 0.125 * log2(e): folded into Q projection so attn uses raw v_exp_f32 (exp2)
#define SCALE_Q 0.18033688011112043f

// swizzled short-index of 16B chunk c in row r of a 64-short-wide LDS tile
#define SW(r, c) (((r) * 64) + ((((c) ^ ((r) & 7))) * 8))

static __device__ __forceinline__ unsigned short f2bf(float f) {
  unsigned int u = __builtin_bit_cast(unsigned int, f);
  u += 0x7FFFu + ((u >> 16) & 1u); // RNE
  return (unsigned short)(u >> 16);
}
static __device__ __forceinline__ unsigned int pk2(float a, float b) {
  return (unsigned int)f2bf(a) | ((unsigned int)f2bf(b) << 16);
}
// fast pack: round-half-up (RNE except exact ties) + single v_perm_b32
static __device__ __forceinline__ unsigned int pk2f(float a, float b) {
  unsigned int ua = __builtin_bit_cast(unsigned int, a) + 0x8000u;
  unsigned int ub = __builtin_bit_cast(unsigned int, b) + 0x8000u;
  return __builtin_amdgcn_perm(ub, ua, 0x07060302u); // [b.3 b.2 a.3 a.2]
}
// convert 8 consecutive fp32 at p to short8 (RNE)
static __device__ __forceinline__ short8 cvt8(const float* p) {
  float4v f0 = *(const float4v*)p;
  float4v f1 = *(const float4v*)(p + 4);
  short8 s;
#pragma unroll
  for (int j = 0; j < 4; ++j) {
    s[j] = (short)f2bf(f0[j]);
    s[4 + j] = (short)f2bf(f1[j]);
  }
  return s;
}

// ---------------- weight conversion kernels ---------------------------------
__global__ __launch_bounds__(256) void cvt3(const float* __restrict__ w0,
                                            const float* __restrict__ w1,
                                            const float* __restrict__ w2,
                                            unsigned short* __restrict__ dst) {
  const float* srcs[3] = {w0, w1, w2};
  const int z = blockIdx.y;
  const float4v* s = (const float4v*)srcs[z];
  uint2* d = (uint2*)(dst + (size_t)z * WSZ);
  int i = blockIdx.x * 256 + threadIdx.x; // < WSZ/4
  float4v f = s[i];
  d[i] = make_uint2(pk2(f[0], f[1]), pk2(f[2], f[3]));
}
__global__ __launch_bounds__(256) void cvt1(const float* __restrict__ w,
                                            unsigned short* __restrict__ dst) {
  int i = blockIdx.x * 256 + threadIdx.x; // < WSZ/4
  float4v f = ((const float4v*)w)[i];
  ((uint2*)dst)[i] = make_uint2(pk2(f[0], f[1]), pk2(f[2], f[3]));
}

// ---------------- full-n QKV projection -------------------------------------
// Block: 64 m-rows x ALL 512 n. X (fp32) converted EXACTLY ONCE per element.
// W is preconverted bf16 (L2-hot, 2MB). z=0: Q (scaled); z=1: K; z=2: V->Vt.
struct QkvB {
  const float* X[3];
  const float* bias[3];
  unsigned short* out[3];
};
__global__ __launch_bounds__(256, 2) void qkv_fulln(QkvB a,
                                                    const unsigned short* __restrict__ Wall) {
  __shared__ unsigned short Xs[64 * 64];  // [m][k] swizzled
  __shared__ unsigned short Ws[512 * 64]; // [n][k] swizzled
  const int z = blockIdx.y;
  const float* __restrict__ X = a.X[z];
  const unsigned short* __restrict__ W = Wall + (size_t)z * WSZ;
  const float* __restrict__ bias = a.bias[z];
  unsigned short* __restrict__ out = a.out[z];
  const int t = threadIdx.x;
  const int w = t >> 6, l = t & 63, lq = l >> 4, lm = l & 15;
  const int mBase = blockIdx.x * 64;
  float4v acc[4][8] = {}; // [m-frag][n-frag], wave covers n in [w*128, w*128+128)

  for (int kc = 0; kc < D_MODEL; kc += 64) {
    __syncthreads();
#pragma unroll
    for (int p = 0; p < 2; ++p) { // X: 64 rows x 8 chunks
      int i = p * 256 + t, r = i >> 3, c = i & 7;
      *(short8*)&Xs[SW(r, c)] = cvt8(&X[(size_t)(mBase + r) * D_MODEL + kc + c * 8]);
    }
#pragma unroll 4
    for (int p = 0; p < 16; ++p) { // W: 512 rows x 8 chunks
      int i = p * 256 + t, r = i >> 3, c = i & 7;
      *(short8*)&Ws[SW(r, c)] = *(const short8*)&W[(size_t)r * D_MODEL + kc + c * 8];
    }
    __syncthreads();
#pragma unroll
    for (int kk = 0; kk < 2; ++kk) {
      short8 av[4];
#pragma unroll
      for (int fm = 0; fm < 4; ++fm)
        av[fm] = *(const short8*)&Xs[SW(fm * 16 + lm, kk * 4 + lq)];
#pragma unroll
      for (int fn = 0; fn < 8; ++fn) {
        short8 bv = *(const short8*)&Ws[SW(w * 128 + fn * 16 + lm, kk * 4 + lq)];
#pragma unroll
        for (int fm = 0; fm < 4; ++fm)
          acc[fm][fn] = __builtin_amdgcn_mfma_f32_16x16x32_bf16(av[fm], bv, acc[fm][fn], 0, 0, 0);
      }
    }
  }
  const int bb = mBase >> 12, s0 = mBase & 4095;
  if (z == 2) {
    // transpose to Vt [b][h][d][s] via LDS (reuse Ws as T[512 n][64 m])
    __syncthreads();
    unsigned short* T = Ws;
#pragma unroll
    for (int fn = 0; fn < 8; ++fn) {
      int n = w * 128 + fn * 16 + lm;
      float bv = bias[n];
#pragma unroll
      for (int fm = 0; fm < 4; ++fm) {
        int m0 = fm * 16 + lq * 4;
        uint2 u;
        u.x = pk2(acc[fm][fn][0] + bv, acc[fm][fn][1] + bv);
        u.y = pk2(acc[fm][fn][2] + bv, acc[fm][fn][3] + bv);
        *(uint2*)&T[SW(n, m0 >> 3) + (lq & 1) * 4] = u;
      }
    }
    __syncthreads();
#pragma unroll
    for (int p = 0; p < 16; ++p) { // 512 n-rows x 8 m-chunks
      int i = p * 256 + t, n = i >> 3, cm = i & 7;
      int h = n >> 6, d = n & 63;
      *(short8*)&out[(((size_t)(bb * NUM_HEADS + h) * DEPTH + d) << 12) + s0 + cm * 8] =
          *(const short8*)&T[SW(n, cm)];
    }
  } else {
    const float scale = (z == 0) ? SCALE_Q : 1.0f;
#pragma unroll
    for (int fn = 0; fn < 8; ++fn) {
      int gn = w * 128 + fn * 16 + lm;
      float bv = bias[gn];
      int h = gn >> 6, d = gn & 63;
#pragma unroll
      for (int fm = 0; fm < 4; ++fm) {
#pragma unroll
        for (int r = 0; r < 4; ++r) {
          int s = s0 + fm * 16 + lq * 4 + r;
          out[(((size_t)(bb * NUM_HEADS + h) * SEQ + s) << 6) + d] =
              f2bf((acc[fm][fn][r] + bv) * scale);
        }
      }
    }
  }
}

// ---------------- 128x64-tile output projection (bf16 X, bf16 W) ------------
__global__ __launch_bounds__(256) void gemm_out_128x64(
    const unsigned short* __restrict__ X, // AO bf16 [8192][512]
    const unsigned short* __restrict__ W, // bf16 [512][512]
    const float* __restrict__ bias,
    float* __restrict__ out) {
  __shared__ unsigned short As[128 * 64];
  __shared__ unsigned short Bs[64 * 64];
  const int t = threadIdx.x;
  const int w = t >> 6, l = t & 63, lq = l >> 4, lm = l & 15;
  const int mq = w * 32;
  const int mBase = blockIdx.x * 128, nBase = blockIdx.y * 64;
  float4v acc[2][4] = {};
  for (int kc = 0; kc < D_MODEL; kc += 64) {
    __syncthreads();
#pragma unroll
    for (int p = 0; p < 4; ++p) {
      int i = p * 256 + t, r = i >> 3, c = i & 7;
      *(short8*)&As[SW(r, c)] = *(const short8*)&X[(size_t)(mBase + r) * D_MODEL + kc + c * 8];
    }
#pragma unroll
    for (int p = 0; p < 2; ++p) {
      int i = p * 256 + t, r = i >> 3, c = i & 7;
      *(short8*)&Bs[SW(r, c)] = *(const short8*)&W[(size_t)(nBase + r) * D_MODEL + kc + c * 8];
    }
    __syncthreads();
#pragma unroll
    for (int kk = 0; kk < 2; ++kk) {
      short8 av[2];
#pragma unroll
      for (int fm = 0; fm < 2; ++fm)
        av[fm] = *(const short8*)&As[SW(mq + fm * 16 + lm, kk * 4 + lq)];
#pragma unroll
      for (int fn = 0; fn < 4; ++fn) {
        short8 bv = *(const short8*)&Bs[SW(fn * 16 + lm, kk * 4 + lq)];
#pragma unroll
        for (int fm = 0; fm < 2; ++fm)
          acc[fm][fn] = __builtin_amdgcn_mfma_f32_16x16x32_bf16(av[fm], bv, acc[fm][fn], 0, 0, 0);
      }
    }
  }
#pragma unroll
  for (int fn = 0; fn < 4; ++fn) {
    int gn = nBase + fn * 16 + lm;
    float bv = bias[gn];
#pragma unroll
    for (int fm = 0; fm < 2; ++fm) {
#pragma unroll
      for (int r = 0; r < 4; ++r) {
        int gm = mBase + mq + fm * 16 + lq * 4 + r;
        out[(size_t)gm * D_MODEL + gn] = acc[fm][fn][r] + bv;
      }
    }
  }
}

// ---------------- fused attention: barrier-free k-split ---------------------
// R3 diagnosis: q-split geometries are pinned at ~114us by twin walls
// (LDS-BW when waves duplicate K/V reads; latency when they don't).
// New structure: block = 64 q-rows, 4 waves; wave w owns k-rows
// [w*16, w*16+16) of EVERY 64-k tile. K,V fragments load global->reg
// (L2-hot). Swapped-QK output P[q=lm][k=lq*4+r] IS the 16x16x16 A-frag
// layout, so P never leaves registers. The k-loop has ZERO LDS ops and
// ZERO barriers. One fp32 cross-wave reduction at the end.
__global__ __launch_bounds__(256, 2) void attn(
    const unsigned short* __restrict__ Qh, // [bh][s][d] (pre-scaled)
    const unsigned short* __restrict__ Kh, // [bh][s][d]
    const unsigned short* __restrict__ Vt, // [bh][d][s]
    unsigned short* __restrict__ AO)       // [b][s][h*64+d] = [8192][512]
{
  __shared__ float Red[4][64 * 65];  // per-wave partial O, padded stride
  __shared__ float RedS[4][64];      // per-wave partial row-sums
  const int t = threadIdx.x;
  const int w = t >> 6; // wave 0..3 = k-slice owner
  const int l = t & 63, lq = l >> 4, lm = l & 15;
  const int bh = blockIdx.y;
  const size_t base = (size_t)bh * SEQ * DEPTH;
  const int qbase = blockIdx.x * 64;
  // lane-resolved row bases
  const unsigned short* __restrict__ Kp =
      Kh + base + (size_t)(w * 16 + lm) * DEPTH;          // k-row for this lane
  const unsigned short* __restrict__ vrow =
      Vt + base + (size_t)lm * SEQ + w * 16 + lq * 4;     // d-row, s-offset

  // Q fragments: ALL 64 q-rows of the block (B-operand of swapped QK, x32)
  short8 qf[4][2];
#pragma unroll
  for (int qt = 0; qt < 4; ++qt)
#pragma unroll
    for (int kk = 0; kk < 2; ++kk)
      qf[qt][kk] = *(const short8*)&Qh[base + (size_t)(qbase + qt * 16 + lm) * DEPTH + kk * 32 + lq * 8];

  bf16x4 ones4;
#pragma unroll
  for (int j = 0; j < 4; ++j) ones4[j] = (short)0x3F80;

  float4v oacc[4][4] = {}; // [qt][dt]: O-partial [q=qt*16+lq*4+r][d=dt*16+lm]
  float4v sumacc[4] = {};  // [qt]: row-sum partial, broadcast over lm

  auto prefetch = [&](short8* kf, bf16x4* vf, int tl) {
    const unsigned short* kp2 = Kp + (size_t)tl * (64 * DEPTH);
    const unsigned short* vp2 = vrow + tl * 64;
#pragma unroll
    for (int kk = 0; kk < 2; ++kk)
      kf[kk] = *(const short8*)&kp2[kk * 32 + lq * 8];
#pragma unroll
    for (int dt = 0; dt < 4; ++dt)
      vf[dt] = *(const bf16x4*)&vp2[dt * 16 * SEQ];
  };
  auto compute = [&](const short8* kf, const bf16x4* vf) {
#pragma unroll
    for (int qt = 0; qt < 4; ++qt) {
      float4v sacc = {};
      sacc = __builtin_amdgcn_mfma_f32_16x16x32_bf16(kf[0], qf[qt][0], sacc, 0, 0, 0);
      sacc = __builtin_amdgcn_mfma_f32_16x16x32_bf16(kf[1], qf[qt][1], sacc, 0, 0, 0);
      uint2 u;
      u.x = pk2f(__builtin_amdgcn_exp2f(sacc[0]), __builtin_amdgcn_exp2f(sacc[1]));
      u.y = pk2f(__builtin_amdgcn_exp2f(sacc[2]), __builtin_amdgcn_exp2f(sacc[3]));
      bf16x4 pa = __builtin_bit_cast(bf16x4, u); // A-frag: [q=lm][k=lq*4+j]
      sumacc[qt] = __builtin_amdgcn_mfma_f32_16x16x16bf16_1k(pa, ones4, sumacc[qt], 0, 0, 0);
#pragma unroll
      for (int dt = 0; dt < 4; ++dt)
        oacc[qt][dt] = __builtin_amdgcn_mfma_f32_16x16x16bf16_1k(pa, vf[dt], oacc[qt][dt], 0, 0, 0);
    }
  };

  short8 kfA[2], kfB[2];
  bf16x4 vfA[4], vfB[4];
  prefetch(kfA, vfA, 0);
  for (int tile = 0; tile < 64; tile += 2) {
    prefetch(kfB, vfB, tile + 1);
    compute(kfA, vfA);
    if (tile + 2 < 64) prefetch(kfA, vfA, tile + 2);
    compute(kfB, vfB);
  }

  // ---- cross-wave reduction (once per block) ----
#pragma unroll
  for (int qt = 0; qt < 4; ++qt)
#pragma unroll
    for (int dt = 0; dt < 4; ++dt)
#pragma unroll
      for (int r = 0; r < 4; ++r)
        Red[w][(qt * 16 + lq * 4 + r) * 65 + dt * 16 + lm] = oacc[qt][dt][r];
  if (lm == 0) {
#pragma unroll
    for (int qt = 0; qt < 4; ++qt)
#pragma unroll
      for (int r = 0; r < 4; ++r)
        RedS[w][qt * 16 + lq * 4 + r] = sumacc[qt][r];
  }
  __syncthreads();
  const int bb = bh >> 3, h = bh & 7;
#pragma unroll 4
  for (int qq = 0; qq < 16; ++qq) {
    int q = w * 16 + qq;
    float s = RedS[0][q] + RedS[1][q] + RedS[2][q] + RedS[3][q];
    float rinv = 1.0f / s;
    float a = Red[0][q * 65 + l] + Red[1][q * 65 + l] +
              Red[2][q * 65 + l] + Red[3][q * 65 + l];
    AO[((size_t)(bb * SEQ + qbase + q)) * D_MODEL + h * DEPTH + l] = f2bf(a * rinv);
  }
}

extern "C" void kernel_launch(void* const* d_in, const int* in_sizes, int n_in,
                              void* d_out, int out_size, void* d_ws, size_t ws_size,
                              hipStream_t stream) {
  const float* q = (const float*)d_in[0];
  const float* k = (const float*)d_in[1];
  const float* v = (const float*)d_in[2];
  const float* wq = (const float*)d_in[3];
  const float* bq = (const float*)d_in[4];
  const float* wk = (const float*)d_in[5];
  const float* bk = (const float*)d_in[6];
  const float* wv = (const float*)d_in[7];
  const float* bv = (const float*)d_in[8];
  const float* wo = (const float*)d_in[9];
  const float* bo = (const float*)d_in[10];

  const size_t HSD = (size_t)BATCH * NUM_HEADS * SEQ * DEPTH; // 4,194,304
  unsigned short* ws = (unsigned short*)d_ws;
  unsigned short* Qh = ws;
  unsigned short* Kh = Qh + HSD;
  unsigned short* Vt = Kh + HSD;
  unsigned short* AO = Vt + HSD; // total 33.6 MB — proven capacity
  // Wqkv (bf16, 1.5 MB) lives in the AO region: consumed by qkv_fulln BEFORE
  // attn overwrites AO. Wo (bf16, 0.5 MB) goes into Vt AFTER attn is done.
  unsigned short* Wqkv = AO;
  unsigned short* Wo = Vt;

  cvt3<<<dim3(WSZ / 4 / 256, 3), 256, 0, stream>>>(wq, wk, wv, Wqkv);

  QkvB qa;
  qa.X[0] = q; qa.X[1] = k; qa.X[2] = v;
  qa.bias[0] = bq; qa.bias[1] = bk; qa.bias[2] = bv;
  qa.out[0] = Qh; qa.out[1] = Kh; qa.out[2] = Vt;
  qkv_fulln<<<dim3(MROWS / 64, 3), 256, 0, stream>>>(qa, Wqkv);

  attn<<<dim3(SEQ / 64, BATCH * NUM_HEADS), 256, 0, stream>>>(Qh, Kh, Vt, AO);

  cvt1<<<WSZ / 4 / 256, 256, 0, stream>>>(wo, Wo);

  gemm_out_128x64<<<dim3(MROWS / 128, D_MODEL / 64), 256, 0, stream>>>(AO, Wo, bo, (float*)d_out);
}

// Round 5
// 246.086 us; speedup vs baseline: 1.2925x; 1.2925x over previous
//
#include <hip/hip_runtime.h>

typedef __attribute__((ext_vector_type(8))) short short8;
typedef __attribute__((ext_vector_type(4))) short bf16x4;
typedef __attribute__((ext_vector_type(4))) float float4v;

#define D_MODEL 512
#define NUM_HEADS 8
#define DEPTH 64
#define SEQ 4096
#define BATCH 2
#define MROWS 8192
#define WSZ (D_MODEL * D_MODEL) // 262144
// 0.125 * log2(e): folded into Q projection so attn uses raw v_exp_f32 (exp2)
#define SCALE_Q 0.18033688011112043f

// swizzled short-index of 16B chunk c in row r of a 64-short-wide LDS tile
#define SW(r, c) (((r) * 64) + ((((c) ^ ((r) & 7))) * 8))

static __device__ __forceinline__ unsigned short f2bf(float f) {
  unsigned int u = __builtin_bit_cast(unsigned int, f);
  u += 0x7FFFu + ((u >> 16) & 1u); // RNE
  return (unsigned short)(u >> 16);
}
static __device__ __forceinline__ unsigned int pk2(float a, float b) {
  return (unsigned int)f2bf(a) | ((unsigned int)f2bf(b) << 16);
}
// fast pack: round-half-up (RNE except exact ties) + single v_perm_b32
static __device__ __forceinline__ unsigned int pk2f(float a, float b) {
  unsigned int ua = __builtin_bit_cast(unsigned int, a) + 0x8000u;
  unsigned int ub = __builtin_bit_cast(unsigned int, b) + 0x8000u;
  return __builtin_amdgcn_perm(ub, ua, 0x07060302u); // [b.3 b.2 a.3 a.2]
}
// convert 8 consecutive fp32 at p to short8 (RNE)
static __device__ __forceinline__ short8 cvt8(const float* p) {
  float4v f0 = *(const float4v*)p;
  float4v f1 = *(const float4v*)(p + 4);
  short8 s;
#pragma unroll
  for (int j = 0; j < 4; ++j) {
    s[j] = (short)f2bf(f0[j]);
    s[4 + j] = (short)f2bf(f1[j]);
  }
  return s;
}

// ---------------- weight conversion kernels ---------------------------------
__global__ __launch_bounds__(256) void cvt3(const float* __restrict__ w0,
                                            const float* __restrict__ w1,
                                            const float* __restrict__ w2,
                                            unsigned short* __restrict__ dst) {
  const float* srcs[3] = {w0, w1, w2};
  const int z = blockIdx.y;
  const float4v* s = (const float4v*)srcs[z];
  uint2* d = (uint2*)(dst + (size_t)z * WSZ);
  int i = blockIdx.x * 256 + threadIdx.x; // < WSZ/4
  float4v f = s[i];
  d[i] = make_uint2(pk2(f[0], f[1]), pk2(f[2], f[3]));
}
__global__ __launch_bounds__(256) void cvt1(const float* __restrict__ w,
                                            unsigned short* __restrict__ dst) {
  int i = blockIdx.x * 256 + threadIdx.x; // < WSZ/4
  float4v f = ((const float4v*)w)[i];
  ((uint2*)dst)[i] = make_uint2(pk2(f[0], f[1]), pk2(f[2], f[3]));
}

// ---------------- full-n QKV projection -------------------------------------
// Block: 64 m-rows x ALL 512 n. X (fp32) converted EXACTLY ONCE per element.
// W is preconverted bf16 (L2-hot, 2MB). z=0: Q (scaled); z=1: K; z=2: V->Vt.
struct QkvB {
  const float* X[3];
  const float* bias[3];
  unsigned short* out[3];
};
__global__ __launch_bounds__(256, 2) void qkv_fulln(QkvB a,
                                                    const unsigned short* __restrict__ Wall) {
  __shared__ unsigned short Xs[64 * 64];  // [m][k] swizzled
  __shared__ unsigned short Ws[512 * 64]; // [n][k] swizzled
  const int z = blockIdx.y;
  const float* __restrict__ X = a.X[z];
  const unsigned short* __restrict__ W = Wall + (size_t)z * WSZ;
  const float* __restrict__ bias = a.bias[z];
  unsigned short* __restrict__ out = a.out[z];
  const int t = threadIdx.x;
  const int w = t >> 6, l = t & 63, lq = l >> 4, lm = l & 15;
  const int mBase = blockIdx.x * 64;
  float4v acc[4][8] = {}; // [m-frag][n-frag], wave covers n in [w*128, w*128+128)

  for (int kc = 0; kc < D_MODEL; kc += 64) {
    __syncthreads();
#pragma unroll
    for (int p = 0; p < 2; ++p) { // X: 64 rows x 8 chunks
      int i = p * 256 + t, r = i >> 3, c = i & 7;
      *(short8*)&Xs[SW(r, c)] = cvt8(&X[(size_t)(mBase + r) * D_MODEL + kc + c * 8]);
    }
#pragma unroll 4
    for (int p = 0; p < 16; ++p) { // W: 512 rows x 8 chunks
      int i = p * 256 + t, r = i >> 3, c = i & 7;
      *(short8*)&Ws[SW(r, c)] = *(const short8*)&W[(size_t)r * D_MODEL + kc + c * 8];
    }
    __syncthreads();
#pragma unroll
    for (int kk = 0; kk < 2; ++kk) {
      short8 av[4];
#pragma unroll
      for (int fm = 0; fm < 4; ++fm)
        av[fm] = *(const short8*)&Xs[SW(fm * 16 + lm, kk * 4 + lq)];
#pragma unroll
      for (int fn = 0; fn < 8; ++fn) {
        short8 bv = *(const short8*)&Ws[SW(w * 128 + fn * 16 + lm, kk * 4 + lq)];
#pragma unroll
        for (int fm = 0; fm < 4; ++fm)
          acc[fm][fn] = __builtin_amdgcn_mfma_f32_16x16x32_bf16(av[fm], bv, acc[fm][fn], 0, 0, 0);
      }
    }
  }
  const int bb = mBase >> 12, s0 = mBase & 4095;
  if (z == 2) {
    // transpose to Vt [b][h][d][s] via LDS (reuse Ws as T[512 n][64 m])
    __syncthreads();
    unsigned short* T = Ws;
#pragma unroll
    for (int fn = 0; fn < 8; ++fn) {
      int n = w * 128 + fn * 16 + lm;
      float bv = bias[n];
#pragma unroll
      for (int fm = 0; fm < 4; ++fm) {
        int m0 = fm * 16 + lq * 4;
        uint2 u;
        u.x = pk2(acc[fm][fn][0] + bv, acc[fm][fn][1] + bv);
        u.y = pk2(acc[fm][fn][2] + bv, acc[fm][fn][3] + bv);
        *(uint2*)&T[SW(n, m0 >> 3) + (lq & 1) * 4] = u;
      }
    }
    __syncthreads();
#pragma unroll
    for (int p = 0; p < 16; ++p) { // 512 n-rows x 8 m-chunks
      int i = p * 256 + t, n = i >> 3, cm = i & 7;
      int h = n >> 6, d = n & 63;
      *(short8*)&out[(((size_t)(bb * NUM_HEADS + h) * DEPTH + d) << 12) + s0 + cm * 8] =
          *(const short8*)&T[SW(n, cm)];
    }
  } else {
    const float scale = (z == 0) ? SCALE_Q : 1.0f;
#pragma unroll
    for (int fn = 0; fn < 8; ++fn) {
      int gn = w * 128 + fn * 16 + lm;
      float bv = bias[gn];
      int h = gn >> 6, d = gn & 63;
#pragma unroll
      for (int fm = 0; fm < 4; ++fm) {
#pragma unroll
        for (int r = 0; r < 4; ++r) {
          int s = s0 + fm * 16 + lq * 4 + r;
          out[(((size_t)(bb * NUM_HEADS + h) * SEQ + s) << 6) + d] =
              f2bf((acc[fm][fn][r] + bv) * scale);
        }
      }
    }
  }
}

// ---------------- 128x64-tile output projection (bf16 X, bf16 W) ------------
__global__ __launch_bounds__(256) void gemm_out_128x64(
    const unsigned short* __restrict__ X, // AO bf16 [8192][512]
    const unsigned short* __restrict__ W, // bf16 [512][512]
    const float* __restrict__ bias,
    float* __restrict__ out) {
  __shared__ unsigned short As[128 * 64];
  __shared__ unsigned short Bs[64 * 64];
  const int t = threadIdx.x;
  const int w = t >> 6, l = t & 63, lq = l >> 4, lm = l & 15;
  const int mq = w * 32;
  const int mBase = blockIdx.x * 128, nBase = blockIdx.y * 64;
  float4v acc[2][4] = {};
  for (int kc = 0; kc < D_MODEL; kc += 64) {
    __syncthreads();
#pragma unroll
    for (int p = 0; p < 4; ++p) {
      int i = p * 256 + t, r = i >> 3, c = i & 7;
      *(short8*)&As[SW(r, c)] = *(const short8*)&X[(size_t)(mBase + r) * D_MODEL + kc + c * 8];
    }
#pragma unroll
    for (int p = 0; p < 2; ++p) {
      int i = p * 256 + t, r = i >> 3, c = i & 7;
      *(short8*)&Bs[SW(r, c)] = *(const short8*)&W[(size_t)(nBase + r) * D_MODEL + kc + c * 8];
    }
    __syncthreads();
#pragma unroll
    for (int kk = 0; kk < 2; ++kk) {
      short8 av[2];
#pragma unroll
      for (int fm = 0; fm < 2; ++fm)
        av[fm] = *(const short8*)&As[SW(mq + fm * 16 + lm, kk * 4 + lq)];
#pragma unroll
      for (int fn = 0; fn < 4; ++fn) {
        short8 bv = *(const short8*)&Bs[SW(fn * 16 + lm, kk * 4 + lq)];
#pragma unroll
        for (int fm = 0; fm < 2; ++fm)
          acc[fm][fn] = __builtin_amdgcn_mfma_f32_16x16x32_bf16(av[fm], bv, acc[fm][fn], 0, 0, 0);
      }
    }
  }
#pragma unroll
  for (int fn = 0; fn < 4; ++fn) {
    int gn = nBase + fn * 16 + lm;
    float bv = bias[gn];
#pragma unroll
    for (int fm = 0; fm < 2; ++fm) {
#pragma unroll
      for (int r = 0; r < 4; ++r) {
        int gm = mBase + mq + fm * 16 + lq * 4 + r;
        out[(size_t)gm * D_MODEL + gn] = acc[fm][fn][r] + bv;
      }
    }
  }
}

// ---------------- fused attention: k-split waves + LDS-staged K/V -----------
// R4 validated the in-register P pipeline (swapped-QK -> exp2 -> pk2f -> pa
// as 16x16x16 A-frag, V as B-frag, cross-wave reduce) but paid VMEM latency
// for per-lane global K/V fragment loads. This version feeds the SAME
// dataflow from coalesced, double-buffered LDS tiles (the R0-R3 staging).
// Block = 64 q-rows, 4 waves; wave w owns k-rows [w*16,w*16+16) of every
// 64-k tile. Per wave-step LDS reads: 2x ds_read_b128 (K) + 4x ds_read_b64
// (V) = 32KB/block-step total (500B/q vs R3's 1KB). No Psub, 1 barrier/step.
// Epilogue: 4-round cross-wave reduce overlaid on Ksub (16KB).
__global__ __launch_bounds__(256, 2) void attn(
    const unsigned short* __restrict__ Qh, // [bh][s][d] (pre-scaled)
    const unsigned short* __restrict__ Kh, // [bh][s][d]
    const unsigned short* __restrict__ Vt, // [bh][d][s]
    unsigned short* __restrict__ AO)       // [b][s][h*64+d] = [8192][512]
{
  __shared__ unsigned short Ksub[2][64 * 64];
  __shared__ unsigned short Vsub[2][64 * 64];
  __shared__ float RedS[4][64];
  const int t = threadIdx.x;
  const int w = t >> 6; // wave 0..3 = k-slice owner
  const int l = t & 63, lq = l >> 4, lm = l & 15;
  const int bh = blockIdx.y;
  const size_t base = (size_t)bh * SEQ * DEPTH;
  const int qbase = blockIdx.x * 64;
  const unsigned short* __restrict__ Kp = Kh + base;
  const unsigned short* __restrict__ Vp = Vt + base;

  // Q fragments: ALL 64 q-rows of the block (B-operand of swapped QK)
  short8 qf[4][2];
#pragma unroll
  for (int qt = 0; qt < 4; ++qt)
#pragma unroll
    for (int kk = 0; kk < 2; ++kk)
      qf[qt][kk] = *(const short8*)&Qh[base + (size_t)(qbase + qt * 16 + lm) * DEPTH + kk * 32 + lq * 8];

  bf16x4 ones4;
#pragma unroll
  for (int j = 0; j < 4; ++j) ones4[j] = (short)0x3F80;

  float4v oacc[4][4] = {}; // [qt][dt]: O[q=qt*16+lq*4+r][d=dt*16+lm] partial
  float4v sum4[4] = {};    // [qt]: row-sum partial (q=qt*16+lq*4+r)
  short8 kreg[2], vreg[2];

#pragma unroll
  for (int p = 0; p < 2; ++p) {
    int i = p * 256 + t, r = i >> 3, c = i & 7;
    kreg[p] = *(const short8*)&Kp[(size_t)r * DEPTH + c * 8];
    vreg[p] = *(const short8*)&Vp[(size_t)r * SEQ + c * 8];
  }
#pragma unroll
  for (int p = 0; p < 2; ++p) {
    int i = p * 256 + t, r = i >> 3, c = i & 7;
    *(short8*)&Ksub[0][SW(r, c)] = kreg[p];
    *(short8*)&Vsub[0][SW(r, c)] = vreg[p];
  }
  __syncthreads();

  // V B-frag LDS address: row d=dt*16+lm, short-col w*16+lq*4
  // -> chunk w*2+(lq>>1), intra-chunk (lq&1)*4 shorts (8B-aligned b64)
  const int vchunk = w * 2 + (lq >> 1), voff = (lq & 1) * 4;

  auto step = [&](int cur, int tile, bool pf) {
    if (pf) {
      const int s0n = (tile + 1) * 64;
#pragma unroll
      for (int p = 0; p < 2; ++p) {
        int i = p * 256 + t, r = i >> 3, c = i & 7;
        kreg[p] = *(const short8*)&Kp[(size_t)(s0n + r) * DEPTH + c * 8];
        vreg[p] = *(const short8*)&Vp[(size_t)r * SEQ + s0n + c * 8];
      }
    }
    short8 kf0 = *(const short8*)&Ksub[cur][SW(w * 16 + lm, lq)];
    short8 kf1 = *(const short8*)&Ksub[cur][SW(w * 16 + lm, 4 + lq)];
    bf16x4 vf[4];
#pragma unroll
    for (int dt = 0; dt < 4; ++dt)
      vf[dt] = *(const bf16x4*)&Vsub[cur][SW(dt * 16 + lm, vchunk) + voff];
#pragma unroll
    for (int qt = 0; qt < 4; ++qt) {
      float4v sacc = {};
      sacc = __builtin_amdgcn_mfma_f32_16x16x32_bf16(kf0, qf[qt][0], sacc, 0, 0, 0);
      sacc = __builtin_amdgcn_mfma_f32_16x16x32_bf16(kf1, qf[qt][1], sacc, 0, 0, 0);
      uint2 u;
      u.x = pk2f(__builtin_amdgcn_exp2f(sacc[0]), __builtin_amdgcn_exp2f(sacc[1]));
      u.y = pk2f(__builtin_amdgcn_exp2f(sacc[2]), __builtin_amdgcn_exp2f(sacc[3]));
      bf16x4 pa = __builtin_bit_cast(bf16x4, u); // A-frag: P^T[q=lm][k=lq*4+i]
      sum4[qt] = __builtin_amdgcn_mfma_f32_16x16x16bf16_1k(pa, ones4, sum4[qt], 0, 0, 0);
#pragma unroll
      for (int dt = 0; dt < 4; ++dt)
        oacc[qt][dt] = __builtin_amdgcn_mfma_f32_16x16x16bf16_1k(pa, vf[dt], oacc[qt][dt], 0, 0, 0);
    }
    if (pf) {
#pragma unroll
      for (int p = 0; p < 2; ++p) {
        int i = p * 256 + t, r = i >> 3, c = i & 7;
        *(short8*)&Ksub[cur ^ 1][SW(r, c)] = kreg[p];
        *(short8*)&Vsub[cur ^ 1][SW(r, c)] = vreg[p];
      }
    }
    __syncthreads();
  };

  for (int it = 0; it < 64; it += 2) {
    step(0, it, true);
    step(1, it + 1, it + 2 < 64);
  }

  // ---- cross-wave reduction: 4 rounds of 16KB overlaid on Ksub ----
  if (lm == 0) {
#pragma unroll
    for (int qt = 0; qt < 4; ++qt)
#pragma unroll
      for (int r = 0; r < 4; ++r)
        RedS[w][qt * 16 + lq * 4 + r] = sum4[qt][r];
  }
  float* Red = (float*)&Ksub[0][0]; // 4096 floats = 16KB
  const int bb = bh >> 3, h = bh & 7;
  const int rq = t >> 2, rd4 = (t & 3) * 4;
#pragma unroll
  for (int dt = 0; dt < 4; ++dt) {
#pragma unroll
    for (int qt = 0; qt < 4; ++qt)
#pragma unroll
      for (int r = 0; r < 4; ++r)
        Red[w * 1024 + (qt * 16 + lq * 4 + r) * 16 + lm] = oacc[qt][dt][r];
    __syncthreads();
    float s = RedS[0][rq] + RedS[1][rq] + RedS[2][rq] + RedS[3][rq];
    float rinv = 1.0f / s;
    float4v a0 = *(const float4v*)&Red[rq * 16 + rd4];
    float4v a1 = *(const float4v*)&Red[1024 + rq * 16 + rd4];
    float4v a2 = *(const float4v*)&Red[2048 + rq * 16 + rd4];
    float4v a3 = *(const float4v*)&Red[3072 + rq * 16 + rd4];
    float4v a;
#pragma unroll
    for (int j = 0; j < 4; ++j) a[j] = (a0[j] + a1[j]) + (a2[j] + a3[j]);
    uint2 u;
    u.x = pk2(a[0] * rinv, a[1] * rinv);
    u.y = pk2(a[2] * rinv, a[3] * rinv);
    *(uint2*)&AO[((size_t)(bb * SEQ + qbase + rq)) * D_MODEL + h * DEPTH + dt * 16 + rd4] = u;
    __syncthreads();
  }
}

extern "C" void kernel_launch(void* const* d_in, const int* in_sizes, int n_in,
                              void* d_out, int out_size, void* d_ws, size_t ws_size,
                              hipStream_t stream) {
  const float* q = (const float*)d_in[0];
  const float* k = (const float*)d_in[1];
  const float* v = (const float*)d_in[2];
  const float* wq = (const float*)d_in[3];
  const float* bq = (const float*)d_in[4];
  const float* wk = (const float*)d_in[5];
  const float* bk = (const float*)d_in[6];
  const float* wv = (const float*)d_in[7];
  const float* bv = (const float*)d_in[8];
  const float* wo = (const float*)d_in[9];
  const float* bo = (const float*)d_in[10];

  const size_t HSD = (size_t)BATCH * NUM_HEADS * SEQ * DEPTH; // 4,194,304
  unsigned short* ws = (unsigned short*)d_ws;
  unsigned short* Qh = ws;
  unsigned short* Kh = Qh + HSD;
  unsigned short* Vt = Kh + HSD;
  unsigned short* AO = Vt + HSD; // total 33.6 MB — proven capacity
  // Wqkv (bf16, 1.5 MB) lives in the AO region: consumed by qkv_fulln BEFORE
  // attn overwrites AO. Wo (bf16, 0.5 MB) goes into Vt AFTER attn is done.
  unsigned short* Wqkv = AO;
  unsigned short* Wo = Vt;

  cvt3<<<dim3(WSZ / 4 / 256, 3), 256, 0, stream>>>(wq, wk, wv, Wqkv);

  QkvB qa;
  qa.X[0] = q; qa.X[1] = k; qa.X[2] = v;
  qa.bias[0] = bq; qa.bias[1] = bk; qa.bias[2] = bv;
  qa.out[0] = Qh; qa.out[1] = Kh; qa.out[2] = Vt;
  qkv_fulln<<<dim3(MROWS / 64, 3), 256, 0, stream>>>(qa, Wqkv);

  attn<<<dim3(SEQ / 64, BATCH * NUM_HEADS), 256, 0, stream>>>(Qh, Kh, Vt, AO);

  cvt1<<<WSZ / 4 / 256, 256, 0, stream>>>(wo, Wo);

  gemm_out_128x64<<<dim3(MROWS / 128, D_MODEL / 64), 256, 0, stream>>>(AO, Wo, bo, (float*)d_out);
}